// Round 7
// baseline (230.538 us; speedup 1.0000x reference)
//
#include <hip/hip_runtime.h>
#include <math.h>

#define BB    8
#define TDIM  64
#define NN    128
#define DD    128
#define TTOUT 62      // T-2
#define W3    384     // 3*N
#define LA    132     // ushort stride: sA/sG 128-wide bf16 rows (264B)
#define LF    36      // ushort stride: sFt/sP 32-wide rows (72B)
#define LWT   68      // ushort stride: sWt 64-wide rows (136B)

typedef __attribute__((ext_vector_type(8))) short bf16x8;
typedef __attribute__((ext_vector_type(4))) float f32x4;

__device__ __forceinline__ float sigf(float x){ return 1.0f/(1.0f+__expf(-x)); }
__device__ __forceinline__ unsigned short f2bf(float x){
  union{float f; unsigned u;} v; v.f=x;
  unsigned r = v.u + 0x7FFFu + ((v.u>>16)&1u);   // RNE
  return (unsigned short)(r>>16);
}
__device__ __forceinline__ float bf2f(unsigned short h){
  union{unsigned u; float f;} t; t.u = (unsigned)h<<16; return t.f;
}

// K_pre: blocks 0..511: per (b,t): rscale, gbf = bf16(G), gbfT = transposed gbf,
//        ssum = fp32 colsum(G).  blocks 512/513: W1/W2 -> transposed bf16.
template<bool TR>
__global__ __launch_bounds__(512) void k_pre(const float* __restrict__ feat,
    const float* __restrict__ w, const float* __restrict__ W1, const float* __restrict__ W2,
    unsigned short* __restrict__ gbf, unsigned short* __restrict__ gbfT,
    float* __restrict__ rscale, float* __restrict__ ssum,
    unsigned short* __restrict__ W1T, unsigned short* __restrict__ W2T){
  __shared__ float sSig[DD];
  __shared__ float sPart[8*DD];
  __shared__ unsigned short sT[DD*LA];
  const int bid = blockIdx.x, tid = threadIdx.x;
  if(bid >= BB*TDIM){
    const float* W = (bid == BB*TDIM) ? W1 : W2;
    unsigned short* WT = (bid == BB*TDIM) ? W1T : W2T;
    for(int e=tid; e<DD*DD; e+=512){
      int k = e>>7, n = e&127;
      WT[n*DD + k] = f2bf(W[(size_t)k*DD + n]);
    }
    return;
  }
  const int bt = bid;
  if(tid < DD) sSig[tid] = sigf(w[tid]);
  __syncthreads();
  const int row = tid >> 2, q = tid & 3;
  const float* fp = feat + ((size_t)bt*NN + row)*DD + q*32;
  float f[32], g[32];
  #pragma unroll
  for(int i=0;i<8;i++){
    float4 v = *(const float4*)(fp + i*4);
    f[i*4]=v.x; f[i*4+1]=v.y; f[i*4+2]=v.z; f[i*4+3]=v.w;
  }
  float ss = 0.f;
  #pragma unroll
  for(int j=0;j<32;j++){ g[j] = f[j]*sSig[q*32+j]; ss += g[j]*g[j]; }
  ss += __shfl_xor(ss,1); ss += __shfl_xor(ss,2);
  float rs = 1.0f / fmaxf(sqrtf(ss), 1e-12f);
  if(q==0) rscale[(size_t)bt*NN + row] = rs;
  #pragma unroll
  for(int j=0;j<32;j++) g[j] *= rs;
  {
    unsigned u[16];
    #pragma unroll
    for(int j=0;j<16;j++) u[j] = (unsigned)f2bf(g[2*j]) | ((unsigned)f2bf(g[2*j+1])<<16);
    uint4* dst = (uint4*)(gbf + ((size_t)bt*NN+row)*DD + q*32);
    #pragma unroll
    for(int i=0;i<4;i++) dst[i] = *(uint4*)&u[i*4];
    if(TR){
      #pragma unroll
      for(int j=0;j<32;j++) sT[(q*32+j)*LA + row] = f2bf(g[j]);
    }
  }
  // column sums of G (fp32, pre-rounding)
  #pragma unroll
  for(int k=4;k<64;k<<=1){
    #pragma unroll
    for(int j=0;j<32;j++) g[j] += __shfl_xor(g[j], k);
  }
  const int lane = tid & 63, wid = tid >> 6;
  if((lane>>2)==0){
    #pragma unroll
    for(int j=0;j<32;j++) sPart[wid*DD + q*32 + j] = g[j];
  }
  __syncthreads();
  if(tid < DD){
    float s = 0.f;
    #pragma unroll
    for(int wv=0; wv<8; wv++) s += sPart[wv*DD + tid];
    ssum[(size_t)bt*DD + tid] = s;
  }
  if(TR){
    const int d = tid>>2, seg = tid&3;
    #pragma unroll
    for(int i=0;i<4;i++){
      uint4 v = *(const uint4*)(sT + d*LA + seg*32 + i*8);
      *(uint4*)(gbfT + (size_t)bt*NN*DD + d*DD + seg*32 + i*8) = v;
    }
  }
}

// K_main: per (b,tt)xhalf: dis; P' = (dm.G)·(cn.G)^T MFMA; agg = P'·G^T/sig; FFN; res+LN
template<bool TR>
__global__ __launch_bounds__(256,4) void k_main(
    const float* __restrict__ feat, const float* __restrict__ w,
    const unsigned short* __restrict__ gbf, const unsigned short* __restrict__ gbfT,
    const float* __restrict__ rscale, const float* __restrict__ ssum,
    const unsigned short* __restrict__ W1T, const float* __restrict__ b1,
    const unsigned short* __restrict__ W2T, const float* __restrict__ b2,
    const float* __restrict__ gamma, const float* __restrict__ beta,
    float* __restrict__ out)
{
  __shared__ __align__(16) unsigned short sm[19584];  // 39,168 B
  __shared__ float sDisC[W3];                          // 1,536 B -> 40,704 total
  unsigned short* sA  = sm;            // 64 x LA  : dm-scaled G rows (own half)
  unsigned short* sG  = sm + 8448;     // 32 x LA  : cn-scaled G chunk
  unsigned short* sFt = sm + 12672;    // 128 x LF : raw G chunk transposed [d][n]
  unsigned short* sP  = sm + 17280;    // 64 x LF  : P' chunk bf16
  unsigned short* sWt = sm + 8448;     // 128 x LWT: FFN weights (overlay, ends 17152)
  float* s3c    = (float*)(sm + 17280);   // prologue temps in sP region
  float* disrow = s3c + DD;               // 384 floats

  const int tid = threadIdx.x;
  const int bid = blockIdx.x;
  const int wg  = (bid & 7)*124 + (bid >> 3);     // XCD-chunked swizzle (992 = 8*124)
  const int bt2 = wg >> 1, half = wg & 1;
  const int mBase = half * 64;
  const int btIdx = (bt2/TTOUT)*TDIM + (bt2%TTOUT);
  const int rowBase = btIdx * NN;
  const int lane = tid & 63, wid = tid >> 6;
  const int l15 = lane & 15, l4 = lane >> 4;
  const int m0 = wid * 16;
  const int p6 = tid & 63, rg6 = tid >> 6;        // TR=false transpose staging

  // ---- prologue: issue long-latency loads first ----
  uint4 rsA[4];
  #pragma unroll
  for(int it=0; it<4; ++it){
    int e = it*256 + tid, r = e>>4, sg = e&15;
    rsA[it] = *(const uint4*)(gbf + (size_t)(rowBase+256+mBase+r)*DD + sg*8);
  }
  uint4 rgA[2];
  #pragma unroll
  for(int k=0;k<2;++k){
    int e = k*256 + tid, r = e>>4, sg = e&15;
    rgA[k] = *(const uint4*)(gbf + (size_t)(rowBase + r)*DD + sg*8);
  }
  uint4 rgB[2]; unsigned rgT[8];
  if(TR){
    #pragma unroll
    for(int k=0;k<2;++k){
      int e = k*256 + tid, d = e>>2, ns = e&3;
      rgB[k] = *(const uint4*)(gbfT + (size_t)btIdx*NN*DD + d*DD + ns*8);
    }
  } else {
    #pragma unroll
    for(int rr=0; rr<2; ++rr)
      #pragma unroll
      for(int i=0;i<4;i++)
        rgT[rr*4+i] = *(const unsigned*)(gbf + (size_t)(rowBase + (rg6*2+rr)*4 + i)*DD + p6*2);
  }
  // s3c = sig * (ssum[t]+ssum[t+1]+ssum[t+2])
  if(tid < DD){
    float s3 = ssum[(size_t)btIdx*DD + tid] + ssum[(size_t)(btIdx+1)*DD + tid]
             + ssum[(size_t)(btIdx+2)*DD + tid];
    s3c[tid] = s3 * sigf(w[tid]);
  }
  __syncthreads();
  // dis pass: deg = rs * (feat_row . s3c), fp32 sign-exact
  #pragma unroll
  for(int rg=0; rg<3; ++rg){
    int row = rg*128 + (tid>>1), h = tid&1;
    const float* fpr = feat + (size_t)(rowBase+row)*DD + h*64;
    float acc = 0.f;
    #pragma unroll
    for(int i=0;i<16;i++){
      float4 v = *(const float4*)(fpr + i*4);
      const float* sc = s3c + h*64 + i*4;
      acc += v.x*sc[0] + v.y*sc[1] + v.z*sc[2] + v.w*sc[3];
    }
    acc += __shfl_xor(acc, 1);
    if(h==0){
      float rs = rscale[rowBase+row];
      float deg = acc * rs;
      float dis = (deg > 0.f) ? rsqrtf(fmaxf(deg, 1e-38f)) : 0.f;
      disrow[row] = dis;
      sDisC[row]  = dis / rs;     // dis * norm (column scale incl. 1/rs)
    }
  }
  __syncthreads();
  // sA = dm-scaled G rows (own 64 rows)
  #pragma unroll
  for(int it=0; it<4; ++it){
    int e = it*256 + tid, r = e>>4, sg = e&15;
    float dm = disrow[256 + mBase + r];
    const unsigned short* s = (const unsigned short*)&rsA[it];
    unsigned short o[8];
    #pragma unroll
    for(int j=0;j<8;j++) o[j] = f2bf(bf2f(s[j]) * dm);
    *(uint4*)(sA + r*LA + sg*8) = *(uint4*)o;
  }
  // chunk0: sG (cn-scaled) + sFt (raw, transposed)
  #pragma unroll
  for(int k=0;k<2;++k){
    int e = k*256 + tid, r = e>>4, sg = e&15;
    float cn = sDisC[r];
    const unsigned short* s = (const unsigned short*)&rgA[k];
    unsigned short o[8];
    #pragma unroll
    for(int j=0;j<8;j++) o[j] = f2bf(bf2f(s[j]) * cn);
    *(uint4*)(sG + r*LA + sg*8) = *(uint4*)o;
  }
  if(TR){
    #pragma unroll
    for(int k=0;k<2;++k){
      int e = k*256 + tid, d = e>>2, ns = e&3;
      *(uint4*)(sFt + d*LF + ns*8) = rgB[k];
    }
  } else {
    #pragma unroll
    for(int rr=0; rr<2; ++rr){
      int r0 = (rg6*2+rr)*4;
      unsigned v0=rgT[rr*4+0], v1=rgT[rr*4+1], v2=rgT[rr*4+2], v3=rgT[rr*4+3];
      uint2 lo, hi;
      lo.x = (v0 & 0xffffu) | (v1 << 16);  lo.y = (v2 & 0xffffu) | (v3 << 16);
      hi.x = (v0 >> 16) | (v1 & 0xffff0000u); hi.y = (v2 >> 16) | (v3 & 0xffff0000u);
      *(uint2*)(sFt + (p6*2  )*LF + r0) = lo;
      *(uint2*)(sFt + (p6*2+1)*LF + r0) = hi;
    }
  }
  __syncthreads();

  // ---- main loop: 12 chunks of 32 window cols ----
  f32x4 acc2[8];
  #pragma unroll
  for(int i=0;i<8;i++) acc2[i] = (f32x4){0.f,0.f,0.f,0.f};

  for(int c=0; c<12; ++c){
    const int n1 = (c+1)*32;
    if(c < 11){   // T14: issue next chunk's loads now, write after barrier
      #pragma unroll
      for(int k=0;k<2;++k){
        int e = k*256 + tid, r = e>>4, sg = e&15;
        rgA[k] = *(const uint4*)(gbf + (size_t)(rowBase + n1 + r)*DD + sg*8);
      }
      if(TR){
        const int tb = n1 >> 7, nn = n1 & 127;
        #pragma unroll
        for(int k=0;k<2;++k){
          int e = k*256 + tid, d = e>>2, ns = e&3;
          rgB[k] = *(const uint4*)(gbfT + (size_t)(btIdx+tb)*NN*DD + d*DD + nn + ns*8);
        }
      } else {
        #pragma unroll
        for(int rr=0; rr<2; ++rr)
          #pragma unroll
          for(int i=0;i<4;i++)
            rgT[rr*4+i] = *(const unsigned*)(gbf + (size_t)(rowBase + n1 + (rg6*2+rr)*4 + i)*DD + p6*2);
      }
    }
    // phase1: P'[own 16 rows, 32 cols] = sA x sG^T (K=128)
    f32x4 p0 = {0.f,0.f,0.f,0.f}, p1 = {0.f,0.f,0.f,0.f};
    #pragma unroll
    for(int ks=0; ks<4; ++ks){
      bf16x8 aA  = *(const bf16x8*)&sA[(m0+l15)*LA + ks*32 + l4*8];
      bf16x8 bg0 = *(const bf16x8*)&sG[( 0+l15)*LA + ks*32 + l4*8];
      bf16x8 bg1 = *(const bf16x8*)&sG[(16+l15)*LA + ks*32 + l4*8];
      p0 = __builtin_amdgcn_mfma_f32_16x16x32_bf16(aA, bg0, p0, 0,0,0);
      p1 = __builtin_amdgcn_mfma_f32_16x16x32_bf16(aA, bg1, p1, 0,0,0);
    }
    #pragma unroll
    for(int r=0;r<4;r++){
      sP[(m0 + l4*4 + r)*LF +  0 + l15] = f2bf(p0[r]);
      sP[(m0 + l4*4 + r)*LF + 16 + l15] = f2bf(p1[r]);
    }
    // phase2 (wave-local sP dependency, no barrier)
    {
      bf16x8 aP = *(const bf16x8*)&sP[(m0+l15)*LF + l4*8];
      #pragma unroll
      for(int dt=0; dt<8; ++dt){
        bf16x8 bF = *(const bf16x8*)&sFt[(dt*16+l15)*LF + l4*8];
        acc2[dt] = __builtin_amdgcn_mfma_f32_16x16x32_bf16(aP, bF, acc2[dt], 0,0,0);
      }
    }
    __syncthreads();   // all reads of sG/sFt done
    if(c < 11){
      #pragma unroll
      for(int k=0;k<2;++k){
        int e = k*256 + tid, r = e>>4, sg = e&15;
        float cn = sDisC[n1 + r];
        const unsigned short* s = (const unsigned short*)&rgA[k];
        unsigned short o[8];
        #pragma unroll
        for(int j=0;j<8;j++) o[j] = f2bf(bf2f(s[j]) * cn);
        *(uint4*)(sG + r*LA + sg*8) = *(uint4*)o;
      }
      if(TR){
        #pragma unroll
        for(int k=0;k<2;++k){
          int e = k*256 + tid, d = e>>2, ns = e&3;
          *(uint4*)(sFt + d*LF + ns*8) = rgB[k];
        }
      } else {
        #pragma unroll
        for(int rr=0; rr<2; ++rr){
          int r0 = (rg6*2+rr)*4;
          unsigned v0=rgT[rr*4+0], v1=rgT[rr*4+1], v2=rgT[rr*4+2], v3=rgT[rr*4+3];
          uint2 lo, hi;
          lo.x = (v0 & 0xffffu) | (v1 << 16);  lo.y = (v2 & 0xffffu) | (v3 << 16);
          hi.x = (v0 >> 16) | (v1 & 0xffff0000u); hi.y = (v2 >> 16) | (v3 & 0xffff0000u);
          *(uint2*)(sFt + (p6*2  )*LF + r0) = lo;
          *(uint2*)(sFt + (p6*2+1)*LF + r0) = hi;
        }
      }
      __syncthreads();   // staged chunk visible
    }
  }

  // agg -> sA (x 1/sig per column), wave-strip-local
  #pragma unroll
  for(int dt=0; dt<8; ++dt){
    float rsig = 1.0f + __expf(-w[dt*16+l15]);   // 1/sigmoid
    #pragma unroll
    for(int r=0;r<4;r++)
      sA[(m0+l4*4+r)*LA + dt*16+l15] = f2bf(acc2[dt][r]*rsig);
  }

  // GEMM1: h = relu(agg @ W1 + b1)
  f32x4 acch[8];
  #pragma unroll
  for(int dt=0; dt<8; ++dt){ float bv = b1[dt*16+l15]; acch[dt] = (f32x4){bv,bv,bv,bv}; }
  for(int kh=0; kh<2; ++kh){
    __syncthreads();
    #pragma unroll
    for(int it=0; it<4; ++it){
      int e = it*256 + tid, n = e>>3, sg = e&7;
      uint4 v = *(const uint4*)(W1T + (size_t)n*DD + kh*64 + sg*8);
      *(uint4*)(sWt + n*LWT + sg*8) = v;
    }
    __syncthreads();
    #pragma unroll
    for(int ks=0; ks<2; ++ks){
      bf16x8 aA = *(const bf16x8*)&sA[(m0+l15)*LA + kh*64 + ks*32 + l4*8];
      #pragma unroll
      for(int dt=0; dt<8; ++dt){
        bf16x8 bW = *(const bf16x8*)&sWt[(dt*16+l15)*LWT + ks*32 + l4*8];
        acch[dt] = __builtin_amdgcn_mfma_f32_16x16x32_bf16(aA, bW, acch[dt], 0,0,0);
      }
    }
  }
  // h -> sA (wave-local rows; barrier at next stage guards sWt)
  #pragma unroll
  for(int dt=0; dt<8; ++dt)
    #pragma unroll
    for(int r=0;r<4;r++)
      sA[(m0+l4*4+r)*LA + dt*16+l15] = f2bf(fmaxf(acch[dt][r], 0.f));

  // GEMM2: o = h @ W2 + b2
  f32x4 acco[8];
  #pragma unroll
  for(int dt=0; dt<8; ++dt){ float bv = b2[dt*16+l15]; acco[dt] = (f32x4){bv,bv,bv,bv}; }
  for(int kh=0; kh<2; ++kh){
    __syncthreads();
    #pragma unroll
    for(int it=0; it<4; ++it){
      int e = it*256 + tid, n = e>>3, sg = e&7;
      uint4 v = *(const uint4*)(W2T + (size_t)n*DD + kh*64 + sg*8);
      *(uint4*)(sWt + n*LWT + sg*8) = v;
    }
    __syncthreads();
    #pragma unroll
    for(int ks=0; ks<2; ++ks){
      bf16x8 aA = *(const bf16x8*)&sA[(m0+l15)*LA + kh*64 + ks*32 + l4*8];
      #pragma unroll
      for(int dt=0; dt<8; ++dt){
        bf16x8 bW = *(const bf16x8*)&sWt[(dt*16+l15)*LWT + ks*32 + l4*8];
        acco[dt] = __builtin_amdgcn_mfma_f32_16x16x32_bf16(aA, bW, acco[dt], 0,0,0);
      }
    }
  }

  // residual + LayerNorm (fp32)
  const float* fres = feat + (size_t)(rowBase + 256 + mBase)*DD;
  #pragma unroll
  for(int r=0;r<4;r++){
    int m = m0 + l4*4 + r;
    float vals[8]; float s1 = 0.f, s2 = 0.f;
    #pragma unroll
    for(int dt=0; dt<8; ++dt){
      int d = dt*16 + l15;
      float v = acco[dt][r] + fres[(size_t)m*DD + d];
      vals[dt] = v; s1 += v; s2 += v*v;
    }
    #pragma unroll
    for(int k=1;k<16;k<<=1){ s1 += __shfl_xor(s1,k); s2 += __shfl_xor(s2,k); }
    float mu   = s1*(1.0f/DD);
    float rstd = rsqrtf(s2*(1.0f/DD) - mu*mu + 1e-5f);
    #pragma unroll
    for(int dt=0; dt<8; ++dt){
      int d = dt*16 + l15;
      out[((size_t)bt2*NN + mBase + m)*DD + d] = (vals[dt]-mu)*rstd*gamma[d] + beta[d];
    }
  }
}

extern "C" void kernel_launch(void* const* d_in, const int* in_sizes, int n_in,
                              void* d_out, int out_size, void* d_ws, size_t ws_size,
                              hipStream_t stream){
  const float* feat  = (const float*)d_in[0];
  const float* w     = (const float*)d_in[1];
  const float* W1    = (const float*)d_in[2];
  const float* b1    = (const float*)d_in[3];
  const float* W2    = (const float*)d_in[4];
  const float* b2    = (const float*)d_in[5];
  const float* gamma = (const float*)d_in[6];
  const float* beta  = (const float*)d_in[7];
  float* out = (float*)d_out;

  char* ws = (char*)d_ws;
  const size_t GSZ = (size_t)BB*TDIM*NN*DD*2;   // 16,777,216
  const bool TR = (ws_size >= 2*GSZ + 262144*2 + 65536);

  unsigned short* gbf  = (unsigned short*)ws;
  unsigned short* gbfT;
  float *rscale, *ssumP;
  unsigned short *W1T, *W2T;
  if(TR){
    gbfT   = (unsigned short*)(ws + GSZ);
    rscale = (float*)(ws + 2*GSZ);
    ssumP  = (float*)(ws + 2*GSZ + 262144);
    W1T    = (unsigned short*)(ws + 2*GSZ + 524288);
    W2T    = (unsigned short*)(ws + 2*GSZ + 557056);
  } else {
    gbfT   = nullptr;
    rscale = (float*)(ws + GSZ);
    ssumP  = (float*)(ws + GSZ + 262144);
    W1T    = (unsigned short*)(ws + GSZ + 524288);
    W2T    = (unsigned short*)(ws + GSZ + 557056);
  }

  if(TR){
    k_pre<true ><<<BB*TDIM+2, 512, 0, stream>>>(feat, w, W1, W2, gbf, gbfT, rscale, ssumP, W1T, W2T);
    k_main<true ><<<BB*TTOUT*2, 256, 0, stream>>>(feat, w, gbf, gbfT, rscale, ssumP,
                                                  W1T, b1, W2T, b2, gamma, beta, out);
  } else {
    k_pre<false><<<BB*TDIM+2, 512, 0, stream>>>(feat, w, W1, W2, gbf, nullptr, rscale, ssumP, W1T, W2T);
    k_main<false><<<BB*TTOUT*2, 256, 0, stream>>>(feat, w, gbf, nullptr, rscale, ssumP,
                                                  W1T, b1, W2T, b2, gamma, beta, out);
  }
}

// Round 8
// 183.047 us; speedup vs baseline: 1.2594x; 1.2594x over previous
//
#include <hip/hip_runtime.h>
#include <math.h>

#define BB    8
#define TDIM  64
#define NN    128
#define DD    128
#define TTOUT 62      // T-2
#define W3    384     // 3*N
#define LA    132     // ushort stride: ovl 128-wide rows (264B)
#define LGS   132     // ushort stride: sG
#define LF    36      // ushort stride: sFt/sP 32-wide rows (72B)
#define LWT   68      // ushort stride: sWt 64-wide rows (136B)

typedef __attribute__((ext_vector_type(8))) short bf16x8;
typedef __attribute__((ext_vector_type(4))) float f32x4;

__device__ __forceinline__ float sigf(float x){ return 1.0f/(1.0f+__expf(-x)); }
__device__ __forceinline__ unsigned short f2bf(float x){
  union{float f; unsigned u;} v; v.f=x;
  unsigned r = v.u + 0x7FFFu + ((v.u>>16)&1u);   // RNE
  return (unsigned short)(r>>16);
}

// K_pre: blocks 0..511: rscale[b,t,n] + ssum[b,t,d] (one feat pass).
//        blocks 512/513: W1/W2 -> transposed bf16.
__global__ __launch_bounds__(512) void k_pre(const float* __restrict__ feat,
    const float* __restrict__ w, const float* __restrict__ W1, const float* __restrict__ W2,
    float* __restrict__ rscale, float* __restrict__ ssum,
    unsigned short* __restrict__ W1T, unsigned short* __restrict__ W2T){
  __shared__ float sSig[DD];
  __shared__ float sPart[8*DD];
  const int bid = blockIdx.x, tid = threadIdx.x;
  if(bid >= BB*TDIM){
    const float* W = (bid == BB*TDIM) ? W1 : W2;
    unsigned short* WT = (bid == BB*TDIM) ? W1T : W2T;
    for(int e=tid; e<DD*DD; e+=512){
      int k = e>>7, n = e&127;
      WT[n*DD + k] = f2bf(W[(size_t)k*DD + n]);
    }
    return;
  }
  const int bt = bid;
  if(tid < DD) sSig[tid] = sigf(w[tid]);
  __syncthreads();
  const int row = tid >> 2, q = tid & 3;
  const float* fp = feat + ((size_t)bt*NN + row)*DD + q*32;
  float g[32];
  #pragma unroll
  for(int i=0;i<8;i++){
    float4 v = *(const float4*)(fp + i*4);
    g[i*4]=v.x; g[i*4+1]=v.y; g[i*4+2]=v.z; g[i*4+3]=v.w;
  }
  float ss = 0.f;
  #pragma unroll
  for(int j=0;j<32;j++){ g[j] *= sSig[q*32+j]; ss += g[j]*g[j]; }
  ss += __shfl_xor(ss,1); ss += __shfl_xor(ss,2);
  float rs = 1.0f / fmaxf(sqrtf(ss), 1e-12f);
  if(q==0) rscale[(size_t)bt*NN + row] = rs;
  #pragma unroll
  for(int j=0;j<32;j++) g[j] *= rs;
  // column sums of G over the 128 rows (fp32)
  #pragma unroll
  for(int k=4;k<64;k<<=1){
    #pragma unroll
    for(int j=0;j<32;j++) g[j] += __shfl_xor(g[j], k);
  }
  const int lane = tid & 63, wid = tid >> 6;
  if((lane>>2)==0){
    #pragma unroll
    for(int j=0;j<32;j++) sPart[wid*DD + q*32 + j] = g[j];
  }
  __syncthreads();
  if(tid < DD){
    float s = 0.f;
    #pragma unroll
    for(int wv=0; wv<8; wv++) s += sPart[wv*DD + tid];
    ssum[(size_t)bt*DD + tid] = s;
  }
}

// K_dis: dis[b,tt,j] = deg>0 ? rsqrt(max(deg,1e-38)) : 0   (round-2 proven)
__global__ void k_dis(const float* __restrict__ feat, const float* __restrict__ w,
                      const float* __restrict__ rscale, const float* __restrict__ ssum,
                      float* __restrict__ dis){
  __shared__ float s3[DD];
  __shared__ float sg[DD];
  int bt2 = blockIdx.x;
  int b = bt2 / TTOUT, tt = bt2 % TTOUT;
  int tid = threadIdx.x;
  if(tid < DD){
    int base = (b*TDIM + tt)*DD;
    s3[tid] = ssum[base+tid] + ssum[base+DD+tid] + ssum[base+2*DD+tid];
    sg[tid] = sigf(w[tid]);
  }
  __syncthreads();
  int gr = (b*TDIM + tt)*NN + tid;
  const float4* fr = (const float4*)(feat + (size_t)gr*DD);
  float deg = 0.f;
  #pragma unroll 8
  for(int q=0;q<DD/4;q++){
    float4 f = fr[q];
    deg += f.x*sg[q*4+0]*s3[q*4+0] + f.y*sg[q*4+1]*s3[q*4+1]
         + f.z*sg[q*4+2]*s3[q*4+2] + f.w*sg[q*4+3]*s3[q*4+3];
  }
  deg *= rscale[gr];
  dis[(size_t)bt2*W3 + tid] = (deg > 0.f) ? rsqrtf(fmaxf(deg, 1e-38f)) : 0.f;
}

// K_main: round-2 core + register-A + double-buffered sG/sFt + 1 barrier/chunk
__global__ __launch_bounds__(512,4) void k_main(
    const float* __restrict__ feat, const float* __restrict__ w,
    const float* __restrict__ rscale, const float* __restrict__ dis,
    const unsigned short* __restrict__ W1T, const float* __restrict__ b1,
    const unsigned short* __restrict__ W2T, const float* __restrict__ b2,
    const float* __restrict__ gamma, const float* __restrict__ beta,
    float* __restrict__ out)
{
  __shared__ __align__(16) unsigned short sm[25600];   // 51,200 B
  __shared__ __align__(16) float sSig[DD];
  __shared__ float sFac[W3];
  // main loop: sG0 @0 (32xLGS), sG1 @4224, sFt0 @8448 (128xLF), sFt1 @13056, sP @17664 (128xLF)
  // FFN overlay: ovl @0 (128xLA=16896), sWt @16896 (128xLWT=8704) -> ends 25600
  unsigned short* sP = sm + 17664;

  const int bid = blockIdx.x, tid = threadIdx.x;
  const int wg = (bid & 7)*62 + (bid >> 3);            // XCD-chunked swizzle (496 = 8*62)
  const int b = wg / TTOUT, tt = wg % TTOUT;
  const int rowBase = (b*TDIM + tt)*NN;
  const float* disP = dis + (size_t)wg*W3;

  const int lane = tid & 63, wid = tid >> 6;
  const int l15 = lane & 15, l4 = lane >> 4;
  const int m0 = wid * 16;

  if(tid < DD) sSig[tid] = sigf(w[tid]);
  if(tid < W3) sFac[tid] = rscale[rowBase+tid] * disP[tid];
  __syncthreads();

  // A fragments (scaled rows 256..383) fully in registers: 16 VGPR/lane
  bf16x8 aReg[4];
  {
    const float* fr = feat + (size_t)(rowBase + 256 + m0 + l15)*DD;
    const float fac = sFac[256 + m0 + l15];
    #pragma unroll
    for(int ks=0; ks<4; ++ks){
      float4 v0 = *(const float4*)(fr + ks*32 + l4*8);
      float4 v1 = *(const float4*)(fr + ks*32 + l4*8 + 4);
      const float* sg = sSig + ks*32 + l4*8;
      unsigned short o[8];
      o[0]=f2bf(v0.x*sg[0]*fac); o[1]=f2bf(v0.y*sg[1]*fac);
      o[2]=f2bf(v0.z*sg[2]*fac); o[3]=f2bf(v0.w*sg[3]*fac);
      o[4]=f2bf(v1.x*sg[4]*fac); o[5]=f2bf(v1.y*sg[5]*fac);
      o[6]=f2bf(v1.z*sg[6]*fac); o[7]=f2bf(v1.w*sg[7]*fac);
      aReg[ks] = *(bf16x8*)o;
    }
  }

  // staging mapping: d = tid&127 fixed; rows rr+e0*16+i
  const int d_s = tid & 127, rr = (tid >> 7)*4;
  float pf[8];

  // stage chunk 0 into buffer 0
  {
    #pragma unroll
    for(int e0=0; e0<2; ++e0)
      #pragma unroll
      for(int i=0;i<4;i++)
        pf[e0*4+i] = feat[(size_t)(rowBase + rr + e0*16 + i)*DD + d_s];
    unsigned short* sGn  = sm;
    unsigned short* sFtn = sm + 8448;
    const float sg = sSig[d_s];
    #pragma unroll
    for(int e0=0; e0<2; ++e0){
      const int r0 = rr + e0*16;
      unsigned short fb[4];
      #pragma unroll
      for(int i=0;i<4;i++){
        float f = pf[e0*4+i];
        fb[i] = f2bf(f);
        sGn[(r0+i)*LGS + d_s] = f2bf(f*sg*sFac[r0+i]);
      }
      unsigned* fp = (unsigned*)&sFtn[d_s*LF + r0];
      fp[0] = (unsigned)fb[0] | ((unsigned)fb[1]<<16);
      fp[1] = (unsigned)fb[2] | ((unsigned)fb[3]<<16);
    }
  }
  __syncthreads();

  f32x4 acc2[8];
  #pragma unroll
  for(int i=0;i<8;i++) acc2[i] = (f32x4){0.f,0.f,0.f,0.f};

  for(int c=0; c<12; ++c){
    const int pOff = c & 1;
    const unsigned short* sGc  = sm + pOff*4224;
    const unsigned short* sFtc = sm + 8448 + pOff*4608;
    // prefetch next chunk (8 floats/thread)
    if(c < 11){
      const int n1 = (c+1)*32;
      #pragma unroll
      for(int e0=0; e0<2; ++e0)
        #pragma unroll
        for(int i=0;i<4;i++)
          pf[e0*4+i] = feat[(size_t)(rowBase + n1 + rr + e0*16 + i)*DD + d_s];
    }
    // phase1: P chunk = Areg x sG^T (K=128)
    f32x4 p0 = {0.f,0.f,0.f,0.f}, p1 = {0.f,0.f,0.f,0.f};
    #pragma unroll
    for(int ks=0; ks<4; ++ks){
      bf16x8 bg0 = *(const bf16x8*)&sGc[( 0+l15)*LGS + ks*32 + l4*8];
      bf16x8 bg1 = *(const bf16x8*)&sGc[(16+l15)*LGS + ks*32 + l4*8];
      p0 = __builtin_amdgcn_mfma_f32_16x16x32_bf16(aReg[ks], bg0, p0, 0,0,0);
      p1 = __builtin_amdgcn_mfma_f32_16x16x32_bf16(aReg[ks], bg1, p1, 0,0,0);
    }
    #pragma unroll
    for(int r=0;r<4;r++){
      sP[(m0+l4*4+r)*LF +  0 + l15] = f2bf(p0[r]);
      sP[(m0+l4*4+r)*LF + 16 + l15] = f2bf(p1[r]);
    }
    // phase2: agg += P x F (wave-local sP)
    {
      bf16x8 aP = *(const bf16x8*)&sP[(m0+l15)*LF + l4*8];
      #pragma unroll
      for(int dt=0; dt<8; ++dt){
        bf16x8 bF = *(const bf16x8*)&sFtc[(dt*16+l15)*LF + l4*8];
        acc2[dt] = __builtin_amdgcn_mfma_f32_16x16x32_bf16(aP, bF, acc2[dt], 0,0,0);
      }
    }
    // write next buffer (other half — no race with current readers)
    if(c < 11){
      unsigned short* sGn  = sm + (pOff^1)*4224;
      unsigned short* sFtn = sm + 8448 + (pOff^1)*4608;
      const int n1 = (c+1)*32;
      const float sg = sSig[d_s];
      #pragma unroll
      for(int e0=0; e0<2; ++e0){
        const int r0 = rr + e0*16;
        unsigned short fb[4];
        #pragma unroll
        for(int i=0;i<4;i++){
          float f = pf[e0*4+i];
          fb[i] = f2bf(f);
          sGn[(r0+i)*LGS + d_s] = f2bf(f*sg*sFac[n1+r0+i]);
        }
        unsigned* fp = (unsigned*)&sFtn[d_s*LF + r0];
        fp[0] = (unsigned)fb[0] | ((unsigned)fb[1]<<16);
        fp[1] = (unsigned)fb[2] | ((unsigned)fb[3]<<16);
      }
    }
    __syncthreads();   // single barrier per chunk
  }

  // ---- FFN: overlay agg/h in ovl (wave-local rows), W tiles in sWt ----
  unsigned short* ovl = sm;
  unsigned short* sWt = sm + 16896;

  #pragma unroll
  for(int dt=0; dt<8; ++dt)
    #pragma unroll
    for(int r=0;r<4;r++)
      ovl[(m0+l4*4+r)*LA + dt*16+l15] = f2bf(acc2[dt][r]);

  // GEMM1: h = relu(agg @ W1 + b1)
  f32x4 acch[8];
  #pragma unroll
  for(int dt=0; dt<8; ++dt){ float bv = b1[dt*16+l15]; acch[dt] = (f32x4){bv,bv,bv,bv}; }
  #pragma unroll
  for(int kh=0; kh<2; ++kh){
    if(kh) __syncthreads();   // prev sWt reads done
    #pragma unroll
    for(int it=0; it<2; ++it){
      int e = it*512 + tid, n = e>>3, sg2 = e&7;
      uint4 v = *(const uint4*)(W1T + (size_t)n*DD + kh*64 + sg2*8);
      *(uint4*)(sWt + n*LWT + sg2*8) = v;
    }
    __syncthreads();
    #pragma unroll
    for(int ks=0; ks<2; ++ks){
      bf16x8 aA = *(const bf16x8*)&ovl[(m0+l15)*LA + kh*64 + ks*32 + l4*8];
      #pragma unroll
      for(int dt=0; dt<8; ++dt){
        bf16x8 bW = *(const bf16x8*)&sWt[(dt*16+l15)*LWT + ks*32 + l4*8];
        acch[dt] = __builtin_amdgcn_mfma_f32_16x16x32_bf16(aA, bW, acch[dt], 0,0,0);
      }
    }
  }
  __syncthreads();   // all sWt reads done before restage
  // h -> ovl (wave-local strip; same-wave DS order guarantees agg reads precede)
  #pragma unroll
  for(int dt=0; dt<8; ++dt)
    #pragma unroll
    for(int r=0;r<4;r++)
      ovl[(m0+l4*4+r)*LA + dt*16+l15] = f2bf(fmaxf(acch[dt][r], 0.f));

  // GEMM2: o = h @ W2 + b2
  f32x4 acco[8];
  #pragma unroll
  for(int dt=0; dt<8; ++dt){ float bv = b2[dt*16+l15]; acco[dt] = (f32x4){bv,bv,bv,bv}; }
  #pragma unroll
  for(int kh=0; kh<2; ++kh){
    if(kh) __syncthreads();
    #pragma unroll
    for(int it=0; it<2; ++it){
      int e = it*512 + tid, n = e>>3, sg2 = e&7;
      uint4 v = *(const uint4*)(W2T + (size_t)n*DD + kh*64 + sg2*8);
      *(uint4*)(sWt + n*LWT + sg2*8) = v;
    }
    __syncthreads();
    #pragma unroll
    for(int ks=0; ks<2; ++ks){
      bf16x8 aA = *(const bf16x8*)&ovl[(m0+l15)*LA + kh*64 + ks*32 + l4*8];
      #pragma unroll
      for(int dt=0; dt<8; ++dt){
        bf16x8 bW = *(const bf16x8*)&sWt[(dt*16+l15)*LWT + ks*32 + l4*8];
        acco[dt] = __builtin_amdgcn_mfma_f32_16x16x32_bf16(aA, bW, acco[dt], 0,0,0);
      }
    }
  }

  // residual + LayerNorm (fp32)
  const float* fres = feat + (size_t)(rowBase + 256)*DD;
  #pragma unroll
  for(int r=0;r<4;r++){
    int m = m0 + l4*4 + r;
    float vals[8]; float s1 = 0.f, s2 = 0.f;
    #pragma unroll
    for(int dt=0; dt<8; ++dt){
      int d = dt*16 + l15;
      float v = acco[dt][r] + fres[(size_t)m*DD + d];
      vals[dt] = v; s1 += v; s2 += v*v;
    }
    #pragma unroll
    for(int k=1;k<16;k<<=1){ s1 += __shfl_xor(s1,k); s2 += __shfl_xor(s2,k); }
    float mu   = s1*(1.0f/DD);
    float rstd = rsqrtf(s2*(1.0f/DD) - mu*mu + 1e-5f);
    #pragma unroll
    for(int dt=0; dt<8; ++dt){
      int d = dt*16 + l15;
      out[((size_t)wg*NN + m)*DD + d] = (vals[dt]-mu)*rstd*gamma[d] + beta[d];
    }
  }
}

extern "C" void kernel_launch(void* const* d_in, const int* in_sizes, int n_in,
                              void* d_out, int out_size, void* d_ws, size_t ws_size,
                              hipStream_t stream){
  const float* feat  = (const float*)d_in[0];
  const float* w     = (const float*)d_in[1];
  const float* W1    = (const float*)d_in[2];
  const float* b1    = (const float*)d_in[3];
  const float* W2    = (const float*)d_in[4];
  const float* b2    = (const float*)d_in[5];
  const float* gamma = (const float*)d_in[6];
  const float* beta  = (const float*)d_in[7];
  float* out = (float*)d_out;

  char* ws = (char*)d_ws;
  float* rscale = (float*)(ws + 0);                       // 262,144 B
  float* ssum   = (float*)(ws + 262144);                  // 262,144 B
  float* dis    = (float*)(ws + 524288);                  // 761,856 B
  unsigned short* W1T = (unsigned short*)(ws + 1286144);  // 32,768 B
  unsigned short* W2T = (unsigned short*)(ws + 1318912);  // 32,768 B

  k_pre<<<BB*TDIM + 2, 512, 0, stream>>>(feat, w, W1, W2, rscale, ssum, W1T, W2T);
  k_dis<<<BB*TTOUT, W3, 0, stream>>>(feat, w, rscale, ssum, dis);
  k_main<<<BB*TTOUT, 512, 0, stream>>>(feat, w, rscale, dis, W1T, b1, W2T, b2,
                                       gamma, beta, out);
}

// Round 9
// 89.824 us; speedup vs baseline: 2.5665x; 2.0378x over previous
//
#include <hip/hip_runtime.h>
#include <math.h>

#define BB    8
#define TDIM  64
#define NN    128
#define DD    128
#define TTOUT 62      // T-2
#define W3    384     // 3*N
#define LG    136     // ushort stride, 128-wide bf16 tiles (272B rows)
#define LP    40      // ushort stride, sFt/sP 32-wide tiles
#define LW    72      // ushort stride, FFN weight tiles (144B rows)

typedef __attribute__((ext_vector_type(8))) short bf16x8;
typedef __attribute__((ext_vector_type(4))) float f32x4;

__device__ __forceinline__ float sigf(float x){ return 1.0f/(1.0f+__expf(-x)); }
__device__ __forceinline__ unsigned short f2bf(float x){
  union{float f; unsigned u;} v; v.f=x;
  unsigned r = v.u + 0x7FFFu + ((v.u>>16)&1u);   // RNE
  return (unsigned short)(r>>16);
}

// K_pre: blocks 0..511: rscale[b,t,n] + ssum[b,t,d] (one feat pass).
//        blocks 512/513: W1/W2 -> transposed bf16.   (proven round 8)
__global__ __launch_bounds__(512) void k_pre(const float* __restrict__ feat,
    const float* __restrict__ w, const float* __restrict__ W1, const float* __restrict__ W2,
    float* __restrict__ rscale, float* __restrict__ ssum,
    unsigned short* __restrict__ W1T, unsigned short* __restrict__ W2T){
  __shared__ float sSig[DD];
  __shared__ float sPart[8*DD];
  const int bid = blockIdx.x, tid = threadIdx.x;
  if(bid >= BB*TDIM){
    const float* W = (bid == BB*TDIM) ? W1 : W2;
    unsigned short* WT = (bid == BB*TDIM) ? W1T : W2T;
    for(int e=tid; e<DD*DD; e+=512){
      int k = e>>7, n = e&127;
      WT[n*DD + k] = f2bf(W[(size_t)k*DD + n]);
    }
    return;
  }
  const int bt = bid;
  if(tid < DD) sSig[tid] = sigf(w[tid]);
  __syncthreads();
  const int row = tid >> 2, q = tid & 3;
  const float* fp = feat + ((size_t)bt*NN + row)*DD + q*32;
  float g[32];
  #pragma unroll
  for(int i=0;i<8;i++){
    float4 v = *(const float4*)(fp + i*4);
    g[i*4]=v.x; g[i*4+1]=v.y; g[i*4+2]=v.z; g[i*4+3]=v.w;
  }
  float ss = 0.f;
  #pragma unroll
  for(int j=0;j<32;j++){ g[j] *= sSig[q*32+j]; ss += g[j]*g[j]; }
  ss += __shfl_xor(ss,1); ss += __shfl_xor(ss,2);
  float rs = 1.0f / fmaxf(sqrtf(ss), 1e-12f);
  if(q==0) rscale[(size_t)bt*NN + row] = rs;
  #pragma unroll
  for(int j=0;j<32;j++) g[j] *= rs;
  // column sums of G over the 128 rows (fp32)
  #pragma unroll
  for(int k=4;k<64;k<<=1){
    #pragma unroll
    for(int j=0;j<32;j++) g[j] += __shfl_xor(g[j], k);
  }
  const int lane = tid & 63, wid = tid >> 6;
  if((lane>>2)==0){
    #pragma unroll
    for(int j=0;j<32;j++) sPart[wid*DD + q*32 + j] = g[j];
  }
  __syncthreads();
  if(tid < DD){
    float s = 0.f;
    #pragma unroll
    for(int wv=0; wv<8; wv++) s += sPart[wv*DD + tid];
    ssum[(size_t)bt*DD + tid] = s;
  }
}

// K_dis: dis[b,tt,j] = deg>0 ? rsqrt(max(deg,1e-38)) : 0   (round-2 proven)
__global__ void k_dis(const float* __restrict__ feat, const float* __restrict__ w,
                      const float* __restrict__ rscale, const float* __restrict__ ssum,
                      float* __restrict__ dis){
  __shared__ float s3[DD];
  __shared__ float sg[DD];
  int bt2 = blockIdx.x;
  int b = bt2 / TTOUT, tt = bt2 % TTOUT;
  int tid = threadIdx.x;
  if(tid < DD){
    int base = (b*TDIM + tt)*DD;
    s3[tid] = ssum[base+tid] + ssum[base+DD+tid] + ssum[base+2*DD+tid];
    sg[tid] = sigf(w[tid]);
  }
  __syncthreads();
  int gr = (b*TDIM + tt)*NN + tid;
  const float4* fr = (const float4*)(feat + (size_t)gr*DD);
  float deg = 0.f;
  #pragma unroll 8
  for(int q=0;q<DD/4;q++){
    float4 f = fr[q];
    deg += f.x*sg[q*4+0]*s3[q*4+0] + f.y*sg[q*4+1]*s3[q*4+1]
         + f.z*sg[q*4+2]*s3[q*4+2] + f.w*sg[q*4+3]*s3[q*4+3];
  }
  deg *= rscale[gr];
  dis[(size_t)bt2*W3 + tid] = (deg > 0.f) ? rsqrtf(fmaxf(deg, 1e-38f)) : 0.f;
}

// K_main: round-2 structure VERBATIM + XCD-chunked swizzle + bf16 W1T/W2T staging
__global__ __launch_bounds__(512,4) void k_main(
    const float* __restrict__ feat,
    const float* __restrict__ w,
    const float* __restrict__ rscale, const float* __restrict__ dis,
    const unsigned short* __restrict__ W1T, const float* __restrict__ b1,
    const unsigned short* __restrict__ W2T, const float* __restrict__ b2,
    const float* __restrict__ gamma, const float* __restrict__ beta,
    float* __restrict__ out)
{
  __shared__ __align__(16) unsigned short sm[32000];   // 64 KB
  __shared__ float sSig[DD];
  unsigned short* sA  = sm;            // 128 x LG : scaled GhL bf16; later agg, then h
  unsigned short* sG  = sm + 17408;    // 32 x LG  : scaled window tile
  unsigned short* sFt = sm + 21760;    // 128 x LP : raw window tile, transposed [d][n]
  unsigned short* sP  = sm + 26880;    // 128 x LP : P chunk bf16
  unsigned short* sWt = sm + 17408;    // 128 x LW : FFN weights (overlays sG+sFt)

  const int tid = threadIdx.x;
  const int bid = blockIdx.x;
  const int bt2 = (bid & 7)*62 + (bid >> 3);   // XCD-chunked swizzle: one batch per XCD L2
  const int rowBase = (bt2/TTOUT)*TDIM*NN + (bt2%TTOUT)*NN;
  const float* disP = dis + (size_t)bt2*W3;

  const int lane = tid & 63, wid = tid >> 6;
  const int l15 = lane & 15, l4 = lane >> 4;
  const int m0 = wid * 16;

  if(tid < DD) sSig[tid] = sigf(w[tid]);
  __syncthreads();

  // prologue: sA = scaled GhL (window rows 256..383) in bf16
  #pragma unroll
  for(int e0=0; e0<8; ++e0){
    int e = e0*512 + tid;            // 4096 elems-of-4
    int d = e & 127, r0 = (e>>7)*4;
    float sg = sSig[d];
    #pragma unroll
    for(int i=0;i<4;i++){
      int j = 256 + r0 + i, gr = rowBase + j;
      float f = feat[(size_t)gr*DD + d];
      float fac = rscale[gr]*disP[j];
      sA[(r0+i)*LG + d] = f2bf(f*sg*fac);
    }
  }

  f32x4 acc2[8];
  #pragma unroll
  for(int i=0;i<8;i++) acc2[i] = (f32x4){0.f,0.f,0.f,0.f};

  for(int c=0; c<12; ++c){
    const int n0 = c*32;
    __syncthreads();   // prev phase2 done with sG/sFt/sP
    // stage sG (scaled bf16, row-major) + sFt (raw bf16, transposed)
    #pragma unroll
    for(int e0=0; e0<2; ++e0){
      int e = e0*512 + tid;          // 1024
      int d = e & 127, r0 = (e>>7)*4;
      float sg = sSig[d];
      unsigned short fb[4];
      #pragma unroll
      for(int i=0;i<4;i++){
        int j = n0 + r0 + i, gr = rowBase + j;
        float f = feat[(size_t)gr*DD + d];
        float fac = rscale[gr]*disP[j];
        fb[i] = f2bf(f);
        sG[(r0+i)*LG + d] = f2bf(f*sg*fac);
      }
      unsigned int* fp = (unsigned int*)&sFt[d*LP + r0];
      fp[0] = (unsigned)fb[0] | ((unsigned)fb[1]<<16);
      fp[1] = (unsigned)fb[2] | ((unsigned)fb[3]<<16);
    }
    __syncthreads();

    // phase1: P[:, n0:n0+32] = GhL(128xK=128) x Gtile^T
    f32x4 p0 = {0.f,0.f,0.f,0.f}, p1 = {0.f,0.f,0.f,0.f};
    #pragma unroll
    for(int ks=0; ks<4; ++ks){
      bf16x8 aA  = *(const bf16x8*)&sA[(m0+l15)*LG + ks*32 + l4*8];
      bf16x8 bg0 = *(const bf16x8*)&sG[( 0+l15)*LG + ks*32 + l4*8];
      bf16x8 bg1 = *(const bf16x8*)&sG[(16+l15)*LG + ks*32 + l4*8];
      p0 = __builtin_amdgcn_mfma_f32_16x16x32_bf16(aA, bg0, p0, 0,0,0);
      p1 = __builtin_amdgcn_mfma_f32_16x16x32_bf16(aA, bg1, p1, 0,0,0);
    }
    #pragma unroll
    for(int r=0;r<4;r++){
      sP[(m0 + l4*4 + r)*LP +  0 + l15] = f2bf(p0[r]);
      sP[(m0 + l4*4 + r)*LP + 16 + l15] = f2bf(p1[r]);
    }
    __syncthreads();

    // phase2: agg += P(128x32) x F(32x128)  [B-frag from transposed sFt]
    bf16x8 aP = *(const bf16x8*)&sP[(m0+l15)*LP + l4*8];
    #pragma unroll
    for(int dt=0; dt<8; ++dt){
      bf16x8 bF = *(const bf16x8*)&sFt[(dt*16+l15)*LP + l4*8];
      acc2[dt] = __builtin_amdgcn_mfma_f32_16x16x32_bf16(aP, bF, acc2[dt], 0,0,0);
    }
  }

  // agg -> sA (bf16); strip-local (D-frag rows == own M-strip)
  #pragma unroll
  for(int dt=0; dt<8; ++dt)
    #pragma unroll
    for(int r=0;r<4;r++)
      sA[(m0+l4*4+r)*LG + dt*16+l15] = f2bf(acc2[dt][r]);

  // GEMM1: h = relu(agg @ W1 + b1)   [W staged from precomputed bf16 W1T]
  f32x4 acch[8];
  #pragma unroll
  for(int dt=0; dt<8; ++dt){
    float bv = b1[dt*16+l15];
    acch[dt] = (f32x4){bv,bv,bv,bv};
  }
  for(int kh=0; kh<2; ++kh){
    __syncthreads();   // all reads of sG/sFt (or prev sWt) done
    #pragma unroll
    for(int it=0; it<2; ++it){
      int e = it*512 + tid, n = e>>3, sg2 = e&7;   // 1024: 128 rows x 8 segs
      uint4 v = *(const uint4*)(W1T + (size_t)n*DD + kh*64 + sg2*8);
      *(uint4*)(sWt + n*LW + sg2*8) = v;
    }
    __syncthreads();
    #pragma unroll
    for(int ks=0; ks<2; ++ks){
      bf16x8 aA = *(const bf16x8*)&sA[(m0+l15)*LG + kh*64 + ks*32 + l4*8];
      #pragma unroll
      for(int dt=0; dt<8; ++dt){
        bf16x8 bW = *(const bf16x8*)&sWt[(dt*16+l15)*LW + ks*32 + l4*8];
        acch[dt] = __builtin_amdgcn_mfma_f32_16x16x32_bf16(aA, bW, acch[dt], 0,0,0);
      }
    }
  }
  __syncthreads();
  // h -> sA (strip-local)
  #pragma unroll
  for(int dt=0; dt<8; ++dt)
    #pragma unroll
    for(int r=0;r<4;r++)
      sA[(m0+l4*4+r)*LG + dt*16+l15] = f2bf(fmaxf(acch[dt][r], 0.f));

  // GEMM2: o = h @ W2 + b2
  f32x4 acco[8];
  #pragma unroll
  for(int dt=0; dt<8; ++dt){
    float bv = b2[dt*16+l15];
    acco[dt] = (f32x4){bv,bv,bv,bv};
  }
  for(int kh=0; kh<2; ++kh){
    __syncthreads();
    #pragma unroll
    for(int it=0; it<2; ++it){
      int e = it*512 + tid, n = e>>3, sg2 = e&7;
      uint4 v = *(const uint4*)(W2T + (size_t)n*DD + kh*64 + sg2*8);
      *(uint4*)(sWt + n*LW + sg2*8) = v;
    }
    __syncthreads();
    #pragma unroll
    for(int ks=0; ks<2; ++ks){
      bf16x8 aA = *(const bf16x8*)&sA[(m0+l15)*LG + kh*64 + ks*32 + l4*8];
      #pragma unroll
      for(int dt=0; dt<8; ++dt){
        bf16x8 bW = *(const bf16x8*)&sWt[(dt*16+l15)*LW + ks*32 + l4*8];
        acco[dt] = __builtin_amdgcn_mfma_f32_16x16x32_bf16(aA, bW, acco[dt], 0,0,0);
      }
    }
  }

  // residual + LayerNorm (fp32)
  const float* fres = feat + (size_t)(rowBase + 256)*DD;
  #pragma unroll
  for(int r=0;r<4;r++){
    int m = m0 + l4*4 + r;
    float vals[8]; float s1 = 0.f, s2 = 0.f;
    #pragma unroll
    for(int dt=0; dt<8; ++dt){
      int d = dt*16 + l15;
      float v = acco[dt][r] + fres[(size_t)m*DD + d];
      vals[dt] = v; s1 += v; s2 += v*v;
    }
    #pragma unroll
    for(int k=1;k<16;k<<=1){ s1 += __shfl_xor(s1,k); s2 += __shfl_xor(s2,k); }
    float mu   = s1*(1.0f/DD);
    float rstd = rsqrtf(s2*(1.0f/DD) - mu*mu + 1e-5f);
    #pragma unroll
    for(int dt=0; dt<8; ++dt){
      int d = dt*16 + l15;
      out[((size_t)bt2*NN + m)*DD + d] = (vals[dt]-mu)*rstd*gamma[d] + beta[d];
    }
  }
}

extern "C" void kernel_launch(void* const* d_in, const int* in_sizes, int n_in,
                              void* d_out, int out_size, void* d_ws, size_t ws_size,
                              hipStream_t stream){
  const float* feat  = (const float*)d_in[0];
  const float* w     = (const float*)d_in[1];
  const float* W1    = (const float*)d_in[2];
  const float* b1    = (const float*)d_in[3];
  const float* W2    = (const float*)d_in[4];
  const float* b2    = (const float*)d_in[5];
  const float* gamma = (const float*)d_in[6];
  const float* beta  = (const float*)d_in[7];
  float* out = (float*)d_out;

  char* ws = (char*)d_ws;
  float* rscale = (float*)(ws + 0);                       // 262,144 B
  float* ssum   = (float*)(ws + 262144);                  // 262,144 B
  float* dis    = (float*)(ws + 524288);                  // 761,856 B
  unsigned short* W1T = (unsigned short*)(ws + 1286144);  // 32,768 B
  unsigned short* W2T = (unsigned short*)(ws + 1318912);  // 32,768 B

  k_pre<<<BB*TDIM + 2, 512, 0, stream>>>(feat, w, W1, W2, rscale, ssum, W1T, W2T);
  k_dis<<<BB*TTOUT, W3, 0, stream>>>(feat, w, rscale, ssum, dis);
  k_main<<<BB*TTOUT, 512, 0, stream>>>(feat, w, rscale, dis, W1T, b1, W2T, b2,
                                       gamma, beta, out);
}